// Round 5
// baseline (429.838 us; speedup 1.0000x reference)
//
#include <hip/hip_runtime.h>

#define HDIM 1024
#define TDIM 17
#define BDIM 64
#define SDIM 512
#define NROWS (BDIM * SDIM) /* 32768 */

// ---------------------------------------------------------------------------
// Kernel 1: feats = x @ W^T + b.  W staged in LDS in two half-K phases
// (34.8 KB -> 4 blocks/CU). 16-way K-split per row, 4 rows per thread.
// ---------------------------------------------------------------------------
__global__ __launch_bounds__(256) void gemm_kernel(
    const float* __restrict__ x, const float* __restrict__ W,
    const float* __restrict__ bias, float* __restrict__ feats) {
  __shared__ __align__(16) float sW[TDIM * 512];  // 34816 B
  int tid = threadIdx.x;
  int sub = tid & 15;  // K-phase within row
  int g = tid >> 4;    // row-group 0..15
  int row0 = blockIdx.x * 64 + g * 4;
  const float* xr = x + (size_t)row0 * HDIM;
  float acc[4][TDIM];
#pragma unroll
  for (int r = 0; r < 4; ++r)
#pragma unroll
    for (int t = 0; t < TDIM; ++t) acc[r][t] = 0.f;

  for (int ph = 0; ph < 2; ++ph) {
    if (ph) __syncthreads();
    for (int i = tid; i < TDIM * 128; i += 256) {
      int t = i >> 7;
      int k = (i & 127) * 4;
      *(float4*)&sW[t * 512 + k] =
          *(const float4*)&W[(size_t)t * HDIM + ph * 512 + k];
    }
    __syncthreads();
#pragma unroll
    for (int c = 0; c < 8; ++c) {
      float4 xv[4];
#pragma unroll
      for (int r = 0; r < 4; ++r)
        xv[r] = *(const float4*)(xr + r * HDIM + ph * 512 + c * 64 + sub * 4);
#pragma unroll
      for (int t = 0; t < TDIM; ++t) {
        float4 wv = *(const float4*)&sW[t * 512 + c * 64 + sub * 4];
#pragma unroll
        for (int r = 0; r < 4; ++r) {
          float a = acc[r][t];
          a = fmaf(xv[r].x, wv.x, a);
          a = fmaf(xv[r].y, wv.y, a);
          a = fmaf(xv[r].z, wv.z, a);
          a = fmaf(xv[r].w, wv.w, a);
          acc[r][t] = a;
        }
      }
    }
  }
#pragma unroll
  for (int r = 0; r < 4; ++r)
#pragma unroll
    for (int t = 0; t < TDIM; ++t) {
#pragma unroll
      for (int m = 1; m < 16; m <<= 1)
        acc[r][t] += __shfl_xor(acc[r][t], m, 64);
    }
#pragma unroll
  for (int r = 0; r < 4; ++r) {
    float val = acc[r][0];
#pragma unroll
    for (int t = 1; t < 16; ++t) val = (sub == t) ? acc[r][t] : val;
    feats[(size_t)(row0 + r) * TDIM + sub] = val + bias[sub];
    if (sub == 0)
      feats[(size_t)(row0 + r) * TDIM + 16] = acc[r][16] + bias[16];
  }
}

// ---------------------------------------------------------------------------
// Kernel 2: Viterbi. One wave per batch. Scores replicated in VGPRs; the
// per-step broadcast is ONE ds_write_b32 (stride-1, conflict-free) + five
// wave-uniform ds_reads (broadcast) -- no readlane/SGPR hazards, no shfl.
// Value+index come from one cndmask pair-tree (exact first-max, R3-proven).
// Backtrace: readlane chase over packed bp words (no LDS in the chain).
// ---------------------------------------------------------------------------
#define FSTRIDE 516
#define BPSTRIDE 520

__global__ __launch_bounds__(64) void viterbi_kernel(
    const float* __restrict__ feats, const float* __restrict__ trans,
    const float* __restrict__ start_t, const float* __restrict__ end_t,
    const int* __restrict__ nwords, float* __restrict__ tags_out) {
  __shared__ __align__(16) float s_fT[TDIM * FSTRIDE];           // 35.1 KB
  __shared__ __align__(16) float s_bc[64];                       // broadcast
  __shared__ __align__(8) unsigned char s_bpT[TDIM * BPSTRIDE];  // 8.8 KB
  __shared__ unsigned char s_tags[SDIM];
  int b = blockIdx.x;
  int lane = threadIdx.x;
  const float* fb = feats + (size_t)b * SDIM * TDIM;
  for (int i4 = lane; i4 < (SDIM * TDIM) / 4; i4 += 64) {
    float4 v = ((const float4*)fb)[i4];
    int base = i4 * 4;
    float vv[4] = {v.x, v.y, v.z, v.w};
#pragma unroll
    for (int e = 0; e < 4; ++e) {
      int idx = base + e;
      s_fT[(idx % TDIM) * FSTRIDE + (idx / TDIM)] = vv[e];
    }
  }
  __syncthreads();

  int nw = nwords[b];
  if (nw < 1) nw = 1;
  if (nw > SDIM) nw = SDIM;
  int jj = lane < TDIM ? lane : TDIM - 1;

  float tcol[TDIM];
#pragma unroll
  for (int i = 0; i < TDIM; ++i) tcol[i] = trans[i * TDIM + jj];

  float s[TDIM];  // replicated scores, VGPR-held in every lane
#pragma unroll
  for (int i = 0; i < TDIM; ++i) s[i] = start_t[i] + s_fT[i * FSTRIDE];

  auto load8 = [&](float* f, int t) {
    float4 a = *(const float4*)&s_fT[jj * FSTRIDE + t];
    float4 c = *(const float4*)&s_fT[jj * FSTRIDE + t + 4];
    f[0] = a.x; f[1] = a.y; f[2] = a.z; f[3] = a.w;
    f[4] = c.x; f[5] = c.y; f[6] = c.z; f[7] = c.w;
  };

  // one Viterbi step; returns this lane's backpointer (exact first-max)
  auto step = [&](float fcu) -> int {
    float v[TDIM];
    int ix[TDIM];
#pragma unroll
    for (int i = 0; i < TDIM; ++i) {
      v[i] = s[i] + tcol[i];
      ix[i] = i;
    }
#define CMB(a, c)              \
  {                            \
    bool p = v[c] > v[a];      \
    v[a] = p ? v[c] : v[a];    \
    ix[a] = p ? ix[c] : ix[a]; \
  }
    CMB(0, 1) CMB(2, 3) CMB(4, 5) CMB(6, 7)
    CMB(8, 9) CMB(10, 11) CMB(12, 13) CMB(14, 15)
    CMB(0, 2) CMB(4, 6) CMB(8, 10) CMB(12, 14)
    CMB(0, 4) CMB(8, 12)
    CMB(0, 8)
    CMB(0, 16)
#undef CMB
    float ns = v[0] + fcu;
    // broadcast: every lane writes its ns (lanes>=17 write harmless copies),
    // then all lanes read the 17 scores back at wave-uniform addresses.
    // DS ops of one wave execute in order -> no barrier needed.
    s_bc[lane] = ns;
    __builtin_amdgcn_wave_barrier();
    float4 a0 = *(const float4*)&s_bc[0];
    float4 a1 = *(const float4*)&s_bc[4];
    float4 a2 = *(const float4*)&s_bc[8];
    float4 a3 = *(const float4*)&s_bc[12];
    float a4 = s_bc[16];
    s[0] = a0.x; s[1] = a0.y; s[2] = a0.z; s[3] = a0.w;
    s[4] = a1.x; s[5] = a1.y; s[6] = a1.z; s[7] = a1.w;
    s[8] = a2.x; s[9] = a2.y; s[10] = a2.z; s[11] = a2.w;
    s[12] = a3.x; s[13] = a3.y; s[14] = a3.z; s[15] = a3.w;
    s[16] = a4;
    return ix[0];
  };

  float fc[8], fn[8];
  load8(fc, 0);
  // ---- chunk 0: steps 1..7 (guarded once) ----
  {
    load8(fn, 8);
    unsigned lo = 0, hi = 0;
#pragma unroll
    for (int u = 1; u < 8; ++u) {
      if (u < nw) {
        int bp = step(fc[u]);
        unsigned by = (unsigned)bp << ((u & 3) * 8);
        if (u < 4) lo |= by; else hi |= by;
      }
    }
    if (lane < TDIM)
      *(unsigned long long*)(s_bpT + lane * BPSTRIDE) =
          (unsigned long long)lo | ((unsigned long long)hi << 32);
#pragma unroll
    for (int u = 0; u < 8; ++u) fc[u] = fn[u];
  }
  // ---- full chunks: branch-free 8-step bodies ----
  int t0 = 8;
  for (; t0 + 8 <= nw; t0 += 8) {
    int tn = (t0 + 8 <= SDIM - 8) ? t0 + 8 : t0;
    load8(fn, tn);
    unsigned lo = 0, hi = 0;
#pragma unroll
    for (int u = 0; u < 8; ++u) {
      int bp = step(fc[u]);
      unsigned by = (unsigned)bp << ((u & 3) * 8);
      if (u < 4) lo |= by; else hi |= by;
    }
    if (lane < TDIM)
      *(unsigned long long*)(s_bpT + lane * BPSTRIDE + t0) =
          (unsigned long long)lo | ((unsigned long long)hi << 32);
#pragma unroll
    for (int u = 0; u < 8; ++u) fc[u] = fn[u];
  }
  // ---- tail chunk (guarded) ----
  if (t0 < nw) {
    unsigned lo = 0, hi = 0;
#pragma unroll
    for (int u = 0; u < 8; ++u) {
      if (t0 + u < nw) {
        int bp = step(fc[u]);
        unsigned by = (unsigned)bp << ((u & 3) * 8);
        if (u < 4) lo |= by; else hi |= by;
      }
    }
    if (lane < TDIM)
      *(unsigned long long*)(s_bpT + lane * BPSTRIDE + t0) =
          (unsigned long long)lo | ((unsigned long long)hi << 32);
  }

  // ---- final argmax (replicated; all lanes identical) ----
  float bv = s[0] + end_t[0];
  int bi = 0;
#pragma unroll
  for (int j = 1; j < TDIM; ++j) {
    float c = s[j] + end_t[j];
    bool p = c > bv;
    bv = p ? c : bv;
    bi = p ? j : bi;
  }
  int tag = __builtin_amdgcn_readfirstlane(bi);

  // ---- backtrace: readlane chase (no LDS in dependency chain) ----
  s_tags[nw - 1] = (unsigned char)tag;
  {
    int tmax = nw - 1;
    int ctop = tmax >> 3;
    unsigned wlo, whi;
    {
      unsigned long long w =
          *(const unsigned long long*)(s_bpT + jj * BPSTRIDE + ctop * 8);
      wlo = (unsigned)w;
      whi = (unsigned)(w >> 32);
    }
    int thi = tmax;
    for (int c = ctop; c >= 0; --c) {
      unsigned nlo = 0, nhi = 0;
      if (c > 0) {
        unsigned long long w =
            *(const unsigned long long*)(s_bpT + jj * BPSTRIDE + (c - 1) * 8);
        nlo = (unsigned)w;
        nhi = (unsigned)(w >> 32);
      }
      int tlo = (c * 8 > 1) ? c * 8 : 1;
      for (int t = thi; t >= tlo; --t) {
        int u = t & 7;
        int rlo = __builtin_amdgcn_readlane((int)wlo, tag);
        int rhi = __builtin_amdgcn_readlane((int)whi, tag);
        int word = (u < 4) ? rlo : rhi;
        tag = (word >> ((u & 3) * 8)) & 0xff;
        s_tags[t - 1] = (unsigned char)tag;
      }
      thi = c * 8 - 1;
      wlo = nlo;
      whi = nhi;
    }
  }
  __syncthreads();
  float* ob = tags_out + (size_t)b * SDIM;
  for (int t = lane; t < SDIM; t += 64)
    ob[t] = (t < nw) ? (float)s_tags[t] : 0.f;
}

// ---------------------------------------------------------------------------
extern "C" void kernel_launch(void* const* d_in, const int* in_sizes, int n_in,
                              void* d_out, int out_size, void* d_ws,
                              size_t ws_size, hipStream_t stream) {
  const float* x = (const float*)d_in[0];
  const float* W = (const float*)d_in[1];
  const float* b = (const float*)d_in[2];
  const float* trans = (const float*)d_in[3];
  const float* start_t = (const float*)d_in[4];
  const float* end_t = (const float*)d_in[5];
  const int* nwords = (const int*)d_in[6];
  float* out = (float*)d_out;
  float* tags_out = out;           // (B, S)
  float* feats_out = out + NROWS;  // (B, S, T)

  gemm_kernel<<<NROWS / 64, 256, 0, stream>>>(x, W, b, feats_out);
  viterbi_kernel<<<BDIM, 64, 0, stream>>>(feats_out, trans, start_t, end_t,
                                          nwords, tags_out);
}

// Round 6
// 399.742 us; speedup vs baseline: 1.0753x; 1.0753x over previous
//
#include <hip/hip_runtime.h>

#define HDIM 1024
#define TDIM 17
#define BDIM 64
#define SDIM 512
#define NROWS (BDIM * SDIM) /* 32768 */

// ---------------------------------------------------------------------------
// Kernel 1: feats = x @ W^T + b.  W staged in LDS in two half-K phases.
// (unchanged from round 4 for attribution)
// ---------------------------------------------------------------------------
__global__ __launch_bounds__(256) void gemm_kernel(
    const float* __restrict__ x, const float* __restrict__ W,
    const float* __restrict__ bias, float* __restrict__ feats) {
  __shared__ __align__(16) float sW[TDIM * 512];  // 34816 B
  int tid = threadIdx.x;
  int sub = tid & 15;
  int g = tid >> 4;
  int row0 = blockIdx.x * 64 + g * 4;
  const float* xr = x + (size_t)row0 * HDIM;
  float acc[4][TDIM];
#pragma unroll
  for (int r = 0; r < 4; ++r)
#pragma unroll
    for (int t = 0; t < TDIM; ++t) acc[r][t] = 0.f;

  for (int ph = 0; ph < 2; ++ph) {
    if (ph) __syncthreads();
    for (int i = tid; i < TDIM * 128; i += 256) {
      int t = i >> 7;
      int k = (i & 127) * 4;
      *(float4*)&sW[t * 512 + k] =
          *(const float4*)&W[(size_t)t * HDIM + ph * 512 + k];
    }
    __syncthreads();
#pragma unroll
    for (int c = 0; c < 8; ++c) {
      float4 xv[4];
#pragma unroll
      for (int r = 0; r < 4; ++r)
        xv[r] = *(const float4*)(xr + r * HDIM + ph * 512 + c * 64 + sub * 4);
#pragma unroll
      for (int t = 0; t < TDIM; ++t) {
        float4 wv = *(const float4*)&sW[t * 512 + c * 64 + sub * 4];
#pragma unroll
        for (int r = 0; r < 4; ++r) {
          float a = acc[r][t];
          a = fmaf(xv[r].x, wv.x, a);
          a = fmaf(xv[r].y, wv.y, a);
          a = fmaf(xv[r].z, wv.z, a);
          a = fmaf(xv[r].w, wv.w, a);
          acc[r][t] = a;
        }
      }
    }
  }
#pragma unroll
  for (int r = 0; r < 4; ++r)
#pragma unroll
    for (int t = 0; t < TDIM; ++t) {
#pragma unroll
      for (int m = 1; m < 16; m <<= 1)
        acc[r][t] += __shfl_xor(acc[r][t], m, 64);
    }
#pragma unroll
  for (int r = 0; r < 4; ++r) {
    float val = acc[r][0];
#pragma unroll
    for (int t = 1; t < 16; ++t) val = (sub == t) ? acc[r][t] : val;
    feats[(size_t)(row0 + r) * TDIM + sub] = val + bias[sub];
    if (sub == 0)
      feats[(size_t)(row0 + r) * TDIM + 16] = acc[r][16] + bias[16];
  }
}

// ---------------------------------------------------------------------------
// Kernel 2: Viterbi via DPP. Lane j (j=lane&15) owns tag j; tag 16 is
// replicated per-lane. Cross-lane score gather = 15 row_ror DPP movs (VALU
// latency, no LDS/SGPR in the chain). Rotation direction is MEASURED at
// init (src[k] = mov_dpp(lane) & 15) so trans indexing is convention-proof.
// Tag-16 update via 4-level DPP butterfly. Exact first-max everywhere.
// ---------------------------------------------------------------------------
#define FSTRIDE 516
#define BPSTRIDE 520

template <int N>
__device__ __forceinline__ int ror_i(int x) {
  return __builtin_amdgcn_mov_dpp(x, 0x120 + N, 0xF, 0xF, false);
}
template <int N>
__device__ __forceinline__ float ror_f(float x) {
  return __uint_as_float((unsigned)__builtin_amdgcn_mov_dpp(
      (int)__float_as_uint(x), 0x120 + N, 0xF, 0xF, false));
}
__device__ __forceinline__ int imin(int a, int b) { return a < b ? a : b; }

__global__ __launch_bounds__(64) void viterbi_kernel(
    const float* __restrict__ feats, const float* __restrict__ trans,
    const float* __restrict__ start_t, const float* __restrict__ end_t,
    const int* __restrict__ nwords, float* __restrict__ tags_out) {
  __shared__ __align__(16) float s_fT[TDIM * FSTRIDE];           // 35.1 KB
  __shared__ __align__(8) unsigned char s_bpT[TDIM * BPSTRIDE];  // 8.8 KB
  __shared__ unsigned char s_tags[SDIM];
  int b = blockIdx.x;
  int lane = threadIdx.x;
  const float* fb = feats + (size_t)b * SDIM * TDIM;
  for (int i4 = lane; i4 < (SDIM * TDIM) / 4; i4 += 64) {
    float4 v = ((const float4*)fb)[i4];
    int base = i4 * 4;
    float vv[4] = {v.x, v.y, v.z, v.w};
#pragma unroll
    for (int e = 0; e < 4; ++e) {
      int idx = base + e;
      s_fT[(idx % TDIM) * FSTRIDE + (idx / TDIM)] = vv[e];
    }
  }
  __syncthreads();

  int nw = nwords[b];
  if (nw < 1) nw = 1;
  if (nw > SDIM) nw = SDIM;
  int colj = lane & 15;

  // measured rotation source lanes (direction-convention-proof)
  int src[16];
  src[0] = colj;
#define SRC(n) src[n] = ror_i<n>(lane) & 15;
  SRC(1) SRC(2) SRC(3) SRC(4) SRC(5) SRC(6) SRC(7) SRC(8)
  SRC(9) SRC(10) SRC(11) SRC(12) SRC(13) SRC(14) SRC(15)
#undef SRC
  float tc[16];  // tc[k] = T[src[k]][colj]
#pragma unroll
  for (int k = 0; k < 16; ++k) tc[k] = trans[src[k] * TDIM + colj];
  float Tj16 = trans[colj * TDIM + 16];
  float T16j = trans[16 * TDIM + colj];
  float T1616 = trans[16 * TDIM + 16];
  float endj = end_t[colj];
  float end16 = end_t[16];

  auto loadF = [&](float* f, float* g, int t) {
    float4 a = *(const float4*)&s_fT[colj * FSTRIDE + t];
    float4 c = *(const float4*)&s_fT[colj * FSTRIDE + t + 4];
    f[0] = a.x; f[1] = a.y; f[2] = a.z; f[3] = a.w;
    f[4] = c.x; f[5] = c.y; f[6] = c.z; f[7] = c.w;
    float4 e = *(const float4*)&s_fT[16 * FSTRIDE + t];
    float4 h = *(const float4*)&s_fT[16 * FSTRIDE + t + 4];
    g[0] = e.x; g[1] = e.y; g[2] = e.z; g[3] = e.w;
    g[4] = h.x; g[5] = h.y; g[6] = h.z; g[7] = h.w;
  };

  float fc[8], g16c[8], fn[8], g16n[8];
  loadF(fc, g16c, 0);
  float sj = start_t[colj] + fc[0];    // lane j's tag-j score
  float s16 = start_t[16] + g16c[0];   // replicated tag-16 score

  // one step; returns bp for own tag (per-lane) and bp16 (replicated in row0)
  auto step = [&](float fj, float f16, int& bpj, int& bp16) {
    float rk[16];
    rk[0] = sj;
#define RK(n) rk[n] = ror_f<n>(sj);
    RK(1) RK(2) RK(3) RK(4) RK(5) RK(6) RK(7) RK(8)
    RK(9) RK(10) RK(11) RK(12) RK(13) RK(14) RK(15)
#undef RK
    float cand[16];
#pragma unroll
    for (int k = 0; k < 16; ++k) cand[k] = rk[k] + tc[k];
    float cand16 = s16 + T16j;
    float m0 = fmaxf(fmaxf(cand[0], cand[1]), cand[2]);
    float m1 = fmaxf(fmaxf(cand[3], cand[4]), cand[5]);
    float m2 = fmaxf(fmaxf(cand[6], cand[7]), cand[8]);
    float m3 = fmaxf(fmaxf(cand[9], cand[10]), cand[11]);
    float m4 = fmaxf(fmaxf(cand[12], cand[13]), cand[14]);
    float m5 = fmaxf(cand[15], cand16);
    float n0 = fmaxf(fmaxf(m0, m1), m2);
    float n1 = fmaxf(fmaxf(m3, m4), m5);
    float maxv = fmaxf(n0, n1);
    float nsj = maxv + fj;
    // exact first-max bp (min tag index among ties)
    int sel[16];
#pragma unroll
    for (int k = 0; k < 16; ++k) sel[k] = (cand[k] == maxv) ? src[k] : 31;
    int q0 = imin(imin(sel[0], sel[1]), sel[2]);
    int q1 = imin(imin(sel[3], sel[4]), sel[5]);
    int q2 = imin(imin(sel[6], sel[7]), sel[8]);
    int q3 = imin(imin(sel[9], sel[10]), sel[11]);
    int q4 = imin(imin(sel[12], sel[13]), sel[14]);
    int q5 = imin(sel[15], (cand16 == maxv) ? 16 : 31);
    bpj = imin(imin(imin(q0, q1), q2), imin(imin(q3, q4), q5));
    // tag-16 update via row butterfly (max over i=0..15, then i=16 merge)
    float c = sj + Tj16;
    float bm = c;
    bm = fmaxf(bm, ror_f<1>(bm));
    bm = fmaxf(bm, ror_f<2>(bm));
    bm = fmaxf(bm, ror_f<4>(bm));
    bm = fmaxf(bm, ror_f<8>(bm));
    int sl = (c == bm) ? colj : 31;
    sl = imin(sl, ror_i<1>(sl));
    sl = imin(sl, ror_i<2>(sl));
    sl = imin(sl, ror_i<4>(sl));
    sl = imin(sl, ror_i<8>(sl));
    float c16o = s16 + T1616;
    bool pg = c16o > bm;
    s16 = (pg ? c16o : bm) + f16;
    bp16 = pg ? 16 : sl;
    sj = nsj;
  };

  // ---- chunk 0: steps 1..7 (guarded once) ----
  {
    loadF(fn, g16n, 8);
    unsigned lo = 0, hi = 0, lo16 = 0, hi16 = 0;
#pragma unroll
    for (int u = 1; u < 8; ++u) {
      if (u < nw) {
        int bpj, bp16;
        step(fc[u], g16c[u], bpj, bp16);
        unsigned sh = (u & 3) * 8;
        if (u < 4) { lo |= (unsigned)bpj << sh; lo16 |= (unsigned)bp16 << sh; }
        else       { hi |= (unsigned)bpj << sh; hi16 |= (unsigned)bp16 << sh; }
      }
    }
    if (lane < 16)
      *(unsigned long long*)(s_bpT + lane * BPSTRIDE) =
          (unsigned long long)lo | ((unsigned long long)hi << 32);
    if (lane == 0)
      *(unsigned long long*)(s_bpT + 16 * BPSTRIDE) =
          (unsigned long long)lo16 | ((unsigned long long)hi16 << 32);
#pragma unroll
    for (int u = 0; u < 8; ++u) { fc[u] = fn[u]; g16c[u] = g16n[u]; }
  }
  // ---- full chunks ----
  int t0 = 8;
  for (; t0 + 8 <= nw; t0 += 8) {
    int tn = (t0 + 8 <= SDIM - 8) ? t0 + 8 : t0;
    loadF(fn, g16n, tn);
    unsigned lo = 0, hi = 0, lo16 = 0, hi16 = 0;
#pragma unroll
    for (int u = 0; u < 8; ++u) {
      int bpj, bp16;
      step(fc[u], g16c[u], bpj, bp16);
      unsigned sh = (u & 3) * 8;
      if (u < 4) { lo |= (unsigned)bpj << sh; lo16 |= (unsigned)bp16 << sh; }
      else       { hi |= (unsigned)bpj << sh; hi16 |= (unsigned)bp16 << sh; }
    }
    if (lane < 16)
      *(unsigned long long*)(s_bpT + lane * BPSTRIDE + t0) =
          (unsigned long long)lo | ((unsigned long long)hi << 32);
    if (lane == 0)
      *(unsigned long long*)(s_bpT + 16 * BPSTRIDE + t0) =
          (unsigned long long)lo16 | ((unsigned long long)hi16 << 32);
#pragma unroll
    for (int u = 0; u < 8; ++u) { fc[u] = fn[u]; g16c[u] = g16n[u]; }
  }
  // ---- tail chunk (guarded) ----
  if (t0 < nw) {
    unsigned lo = 0, hi = 0, lo16 = 0, hi16 = 0;
#pragma unroll
    for (int u = 0; u < 8; ++u) {
      if (t0 + u < nw) {
        int bpj, bp16;
        step(fc[u], g16c[u], bpj, bp16);
        unsigned sh = (u & 3) * 8;
        if (u < 4) { lo |= (unsigned)bpj << sh; lo16 |= (unsigned)bp16 << sh; }
        else       { hi |= (unsigned)bpj << sh; hi16 |= (unsigned)bp16 << sh; }
      }
    }
    if (lane < 16)
      *(unsigned long long*)(s_bpT + lane * BPSTRIDE + t0) =
          (unsigned long long)lo | ((unsigned long long)hi << 32);
    if (lane == 0)
      *(unsigned long long*)(s_bpT + 16 * BPSTRIDE + t0) =
          (unsigned long long)lo16 | ((unsigned long long)hi16 << 32);
  }

  // ---- final argmax over (sj + endj) lanes 0..15, plus s16 + end16 ----
  float aj = sj + endj;
  float bm = aj;
  bm = fmaxf(bm, ror_f<1>(bm));
  bm = fmaxf(bm, ror_f<2>(bm));
  bm = fmaxf(bm, ror_f<4>(bm));
  bm = fmaxf(bm, ror_f<8>(bm));
  int sl = (aj == bm) ? colj : 31;
  sl = imin(sl, ror_i<1>(sl));
  sl = imin(sl, ror_i<2>(sl));
  sl = imin(sl, ror_i<4>(sl));
  sl = imin(sl, ror_i<8>(sl));
  float a16 = s16 + end16;
  int tag0 = (a16 > bm) ? 16 : sl;
  int tag = __builtin_amdgcn_readfirstlane(tag0);

  // ---- backtrace: readlane chase over packed bp rows ----
  int bj = lane < TDIM ? lane : TDIM - 1;
  s_tags[nw - 1] = (unsigned char)tag;
  {
    int tmax = nw - 1;
    int ctop = tmax >> 3;
    unsigned wlo, whi;
    {
      unsigned long long w =
          *(const unsigned long long*)(s_bpT + bj * BPSTRIDE + ctop * 8);
      wlo = (unsigned)w;
      whi = (unsigned)(w >> 32);
    }
    int thi = tmax;
    for (int c = ctop; c >= 0; --c) {
      unsigned nlo = 0, nhi = 0;
      if (c > 0) {
        unsigned long long w =
            *(const unsigned long long*)(s_bpT + bj * BPSTRIDE + (c - 1) * 8);
        nlo = (unsigned)w;
        nhi = (unsigned)(w >> 32);
      }
      int tlo = (c * 8 > 1) ? c * 8 : 1;
      for (int t = thi; t >= tlo; --t) {
        int u = t & 7;
        int rlo = __builtin_amdgcn_readlane((int)wlo, tag);
        int rhi = __builtin_amdgcn_readlane((int)whi, tag);
        int word = (u < 4) ? rlo : rhi;
        tag = (word >> ((u & 3) * 8)) & 0xff;
        s_tags[t - 1] = (unsigned char)tag;
      }
      thi = c * 8 - 1;
      wlo = nlo;
      whi = nhi;
    }
  }
  __syncthreads();
  float* ob = tags_out + (size_t)b * SDIM;
  for (int t = lane; t < SDIM; t += 64)
    ob[t] = (t < nw) ? (float)s_tags[t] : 0.f;
}

// ---------------------------------------------------------------------------
extern "C" void kernel_launch(void* const* d_in, const int* in_sizes, int n_in,
                              void* d_out, int out_size, void* d_ws,
                              size_t ws_size, hipStream_t stream) {
  const float* x = (const float*)d_in[0];
  const float* W = (const float*)d_in[1];
  const float* b = (const float*)d_in[2];
  const float* trans = (const float*)d_in[3];
  const float* start_t = (const float*)d_in[4];
  const float* end_t = (const float*)d_in[5];
  const int* nwords = (const int*)d_in[6];
  float* out = (float*)d_out;
  float* tags_out = out;           // (B, S)
  float* feats_out = out + NROWS;  // (B, S, T)

  gemm_kernel<<<NROWS / 64, 256, 0, stream>>>(x, W, b, feats_out);
  viterbi_kernel<<<BDIM, 64, 0, stream>>>(feats_out, trans, start_t, end_t,
                                          nwords, tags_out);
}